// Round 6
// baseline (259.072 us; speedup 1.0000x reference)
//
#include <hip/hip_runtime.h>
#include <math.h>

#define NROWS 8192
#define DIMX  1024
#define DKV   128
#define KSPLIT 8
#define KEYS_PER_SPLIT (NROWS / KSPLIT)  // 1024
#define BN 64

typedef __attribute__((ext_vector_type(8))) short bf16x8;
typedef __attribute__((ext_vector_type(4))) float f32x4;

static __device__ __forceinline__ short f2bf(float f) {
    union { float f; unsigned u; } v; v.f = f;
    unsigned r = v.u + 0x7fff + ((v.u >> 16) & 1);  // RNE
    return (short)(r >> 16);
}
static __device__ __forceinline__ float bf2f(short s) {
    union { unsigned u; float f; } v; v.u = ((unsigned)(unsigned short)s) << 16;
    return v.f;
}
static __device__ __forceinline__ unsigned pack2(short lo, short hi) {
    return ((unsigned)(unsigned short)hi << 16) | (unsigned short)lo;
}

// ---------------------------------------------------------------------------
// wconv: Wqk, Wv fp32 -> bf16 (1 MB traffic)
// ---------------------------------------------------------------------------
__global__ __launch_bounds__(256) void wconv_kernel(
    const float* __restrict__ Wqk, const float* __restrict__ Wv,
    short* __restrict__ wqb, short* __restrict__ wvb)
{
    const int t = blockIdx.x * 256 + threadIdx.x;   // 0..32767
    const float* src = (t < 16384) ? Wqk : Wv;
    short* dst = (t < 16384) ? wqb : wvb;
    const int off = (t & 16383) * 8;
    const float4 f0 = *(const float4*)(src + off);
    const float4 f1 = *(const float4*)(src + off + 4);
    uint4 p;
    p.x = pack2(f2bf(f0.x), f2bf(f0.y));
    p.y = pack2(f2bf(f0.z), f2bf(f0.w));
    p.z = pack2(f2bf(f1.x), f2bf(f1.y));
    p.w = pack2(f2bf(f1.z), f2bf(f1.w));
    *(uint4*)(dst + off) = p;
}

// ---------------------------------------------------------------------------
// proj: register-direct MFMA, NO inner-loop barriers.
// 256 blocks x 512 threads. Block = 32 rows x 256 cols (q cols 0-127,
// v cols 128-255). Wave (rg=wave>>2, cg=wave&3): 16 rows x 64 cols.
// A from fp32 x (in-register bf16 convert); B from L2-resident bf16 W.
// Epilogue assembles full-line stores via LDS (one barrier total).
// ---------------------------------------------------------------------------
__global__ __launch_bounds__(512) void proj_kernel(
    const float* __restrict__ x,
    const short* __restrict__ wqb, const float* __restrict__ bqk,
    const short* __restrict__ wvb, const float* __restrict__ bv,
    short* __restrict__ qkb, short* __restrict__ vtb)
{
    __shared__ __align__(16) short otq[32 * 136];   // 32 rows x 128 q-cols (+8)
    __shared__ __align__(16) short otv[128 * 40];   // 128 v-cols x 32 rows (+8)

    const int tid = threadIdx.x;
    const int lane = tid & 63, wave = tid >> 6;
    const int l15 = lane & 15, quad = lane >> 4;
    const int cg = wave & 3, rg = wave >> 2;
    const int r0 = blockIdx.x * 32;
    const bool isv = cg >= 2;
    const short* W = isv ? wvb : wqb;
    const float* bias = isv ? bv : bqk;
    const int c0 = (cg & 1) * 64;                   // col offset within its W

    f32x4 acc[4];
    #pragma unroll
    for (int i = 0; i < 4; ++i) acc[i] = (f32x4)0.0f;

    const float* xrow = x + (size_t)(r0 + rg * 16 + l15) * DIMX + quad * 8;
    const short* wp = W + (size_t)(c0 + l15) * DIMX + quad * 8;

    #pragma unroll 2
    for (int k0 = 0; k0 < DIMX; k0 += 32) {
        const float4 f0 = *(const float4*)(xrow + k0);
        const float4 f1 = *(const float4*)(xrow + k0 + 4);
        bf16x8 af;
        af[0] = f2bf(f0.x); af[1] = f2bf(f0.y); af[2] = f2bf(f0.z); af[3] = f2bf(f0.w);
        af[4] = f2bf(f1.x); af[5] = f2bf(f1.y); af[6] = f2bf(f1.z); af[7] = f2bf(f1.w);
        #pragma unroll
        for (int nt = 0; nt < 4; ++nt) {
            const bf16x8 wf = *(const bf16x8*)(wp + (size_t)(nt * 16) * DIMX + k0);
            acc[nt] = __builtin_amdgcn_mfma_f32_16x16x32_bf16(af, wf, acc[nt], 0, 0, 0);
        }
    }

    // C layout: col=l15 (col c0+nt*16+l15), row=quad*4+r (row r0+rg*16+quad*4+r)
    if (!isv) {
        #pragma unroll
        for (int nt = 0; nt < 4; ++nt) {
            const float b = bias[c0 + nt * 16 + l15];
            #pragma unroll
            for (int r = 0; r < 4; ++r)
                otq[(rg * 16 + quad * 4 + r) * 136 + c0 + nt * 16 + l15] = f2bf(acc[nt][r] + b);
        }
    } else {
        #pragma unroll
        for (int nt = 0; nt < 4; ++nt) {
            const float b = bias[c0 + nt * 16 + l15];
            #pragma unroll
            for (int r = 0; r < 4; ++r)
                otv[(c0 + nt * 16 + l15) * 40 + rg * 16 + quad * 4 + r] = f2bf(acc[nt][r] + b);
        }
    }
    __syncthreads();

    // q store: 32 rows x 16 chunks = 512 b128 stores (full 256B rows)
    {
        const int row = tid >> 4, ch = tid & 15;
        *(uint4*)(qkb + (size_t)(r0 + row) * DKV + ch * 8) = *(const uint4*)&otq[row * 136 + ch * 8];
    }
    // v store: 128 cols x 4 chunks = 512 b128 stores (full 64B col-segments)
    {
        const int col = tid >> 2, h = tid & 3;
        *(uint4*)(vtb + (size_t)col * NROWS + r0 + h * 8) = *(const uint4*)&otv[col * 40 + h * 8];
    }
}

// ---------------------------------------------------------------------------
// flash v6: NO inner-loop __syncthreads. K/V fragments read directly from
// L2-resident qkb/vtb. S computed TRANSPOSED (A=K, B=Q) so C col = Q-row:
// fixed-M is one scalar/lane and P-writes are 8x ds_write_b64.
// 4 waves x 32 Q-rows per block; grid (64, KSPLIT); LDS = P buffer only.
// ---------------------------------------------------------------------------
__global__ __launch_bounds__(256, 2) void flash_kernel(
    const short* __restrict__ qkb, const short* __restrict__ vtb,
    float* __restrict__ opart, float* __restrict__ lpart)
{
    __shared__ __align__(16) short pb[4 * 32 * 72];   // per-wave P: 32 x 64 (+8)

    const int tid  = threadIdx.x;
    const int lane = tid & 63;
    const int wave = tid >> 6;
    const int l15  = lane & 15;
    const int quad = lane >> 4;
    const int rbase = blockIdx.x * 128 + wave * 32;
    const int ks = blockIdx.y;

    // Q fragments, used as B operand: B[k=d][n=qrow], n=l15, d=k*32+quad*8+j
    bf16x8 qf[2][4];
    #pragma unroll
    for (int g = 0; g < 2; ++g) {
        const short* qrow = qkb + (size_t)(rbase + g * 16 + l15) * DKV;
        #pragma unroll
        for (int k = 0; k < 4; ++k)
            qf[g][k] = *(const bf16x8*)(qrow + k * 32 + quad * 8);
    }

    // fixed M = |qk_row|^2 for row rbase+g*16+l15 (== S^T col of this lane)
    float M[2];
    #pragma unroll
    for (int g = 0; g < 2; ++g) {
        float ss = 0.f;
        #pragma unroll
        for (int k = 0; k < 4; ++k)
            #pragma unroll
            for (int j = 0; j < 8; ++j) {
                const float q = bf2f(qf[g][k][j]);
                ss += q * q;
            }
        ss += __shfl_xor(ss, 16);
        ss += __shfl_xor(ss, 32);
        M[g] = ss;
    }

    bf16x8 ones;
    #pragma unroll
    for (int i = 0; i < 8; ++i) ones[i] = (short)0x3F80;   // bf16 1.0

    f32x4 oacc[2][8];
    #pragma unroll
    for (int g = 0; g < 2; ++g)
        #pragma unroll
        for (int i = 0; i < 8; ++i) oacc[g][i] = (f32x4)0.0f;
    f32x4 lacc[2];
    lacc[0] = (f32x4)0.0f; lacc[1] = (f32x4)0.0f;

    const int jb = ks * KEYS_PER_SPLIT, je = jb + KEYS_PER_SPLIT;
    short* pw = &pb[wave * 32 * 72];

    for (int j0 = jb; j0 < je; j0 += BN) {
        // keep the block's waves phase-aligned (L1 reuse); no memory fence
        // needed: pb is wave-private, K/V are read-only.
        __builtin_amdgcn_s_barrier();

        // K fragments (A operand: A[m=key][k=d], key=nt*16+l15): all 16 up
        // front so the 16 global loads overlap the MFMA chain.
        bf16x8 kf[4][4];
        #pragma unroll
        for (int nt = 0; nt < 4; ++nt)
            #pragma unroll
            for (int k = 0; k < 4; ++k)
                kf[nt][k] = *(const bf16x8*)(qkb + (size_t)(j0 + nt * 16 + l15) * DKV + k * 32 + quad * 8);

        // S^T = K Q^T : C col=l15=qrow, row=quad*4+r=key offset
        #pragma unroll
        for (int nt = 0; nt < 4; ++nt) {
            #pragma unroll
            for (int g = 0; g < 2; ++g) {
                f32x4 st = (f32x4)0.0f;
                #pragma unroll
                for (int k = 0; k < 4; ++k)
                    st = __builtin_amdgcn_mfma_f32_16x16x32_bf16(kf[nt][k], qf[g][k], st, 0, 0, 0);
                // P: 4 consecutive keys (nt*16+quad*4+r) at qrow g*16+l15
                uint2 pk;
                pk.x = pack2(f2bf(__expf(st[0] - M[g])), f2bf(__expf(st[1] - M[g])));
                pk.y = pack2(f2bf(__expf(st[2] - M[g])), f2bf(__expf(st[3] - M[g])));
                *(uint2*)&pw[(g * 16 + l15) * 72 + nt * 16 + quad * 4] = pk;
            }
        }

        // O += P V ; l += P . 1   (P A-layout: m=l15=qrow, k=kb*32+quad*8+j)
        #pragma unroll
        for (int kb = 0; kb < 2; ++kb) {
            bf16x8 vf[8];
            #pragma unroll
            for (int nt = 0; nt < 8; ++nt)
                vf[nt] = *(const bf16x8*)(vtb + (size_t)(nt * 16 + l15) * NROWS + j0 + kb * 32 + quad * 8);
            const bf16x8 a0 = *(const bf16x8*)&pw[l15 * 72 + kb * 32 + quad * 8];
            const bf16x8 a1 = *(const bf16x8*)&pw[(16 + l15) * 72 + kb * 32 + quad * 8];
            lacc[0] = __builtin_amdgcn_mfma_f32_16x16x32_bf16(a0, ones, lacc[0], 0, 0, 0);
            lacc[1] = __builtin_amdgcn_mfma_f32_16x16x32_bf16(a1, ones, lacc[1], 0, 0, 0);
            #pragma unroll
            for (int nt = 0; nt < 8; ++nt) {
                oacc[0][nt] = __builtin_amdgcn_mfma_f32_16x16x32_bf16(a0, vf[nt], oacc[0][nt], 0, 0, 0);
                oacc[1][nt] = __builtin_amdgcn_mfma_f32_16x16x32_bf16(a1, vf[nt], oacc[1][nt], 0, 0, 0);
            }
        }
    }

    // store partials: fp32 full-line stores.  oacc C layout: col=l15 (d),
    // row=quad*4+r (qrow offset).  lacc same row layout.
    #pragma unroll
    for (int g = 0; g < 2; ++g) {
        const int rw = rbase + g * 16 + quad * 4;
        #pragma unroll
        for (int nt = 0; nt < 8; ++nt) {
            const int col = nt * 16 + l15;
            #pragma unroll
            for (int r = 0; r < 4; ++r)
                opart[((size_t)ks * NROWS + rw + r) * DKV + col] = oacc[g][nt][r];
        }
        if (l15 == 0)
            #pragma unroll
            for (int r = 0; r < 4; ++r)
                lpart[ks * NROWS + rw + r] = lacc[g][r];
    }
}

// ---------------------------------------------------------------------------
// combine: out = sum_s opart / sum_s lpart  (M is split-independent)
// ---------------------------------------------------------------------------
__global__ __launch_bounds__(256) void combine_kernel(
    const float* __restrict__ opart, const float* __restrict__ lpart,
    float* __restrict__ out)
{
    const int idx = blockIdx.x * 256 + threadIdx.x;
    const int row = idx >> 7;
    float L = 0.f, acc = 0.f;
    #pragma unroll
    for (int s = 0; s < KSPLIT; ++s) {
        L += lpart[s * NROWS + row];
        acc += opart[(size_t)s * NROWS * DKV + idx];
    }
    out[idx] = acc / L;
}

// ---------------------------------------------------------------------------
extern "C" void kernel_launch(void* const* d_in, const int* in_sizes, int n_in,
                              void* d_out, int out_size, void* d_ws, size_t ws_size,
                              hipStream_t stream) {
    const float* x   = (const float*)d_in[0];
    const float* Wqk = (const float*)d_in[1];
    const float* bqk = (const float*)d_in[2];
    const float* Wv  = (const float*)d_in[3];
    const float* bv  = (const float*)d_in[4];
    float* out = (float*)d_out;

    char* ws = (char*)d_ws;
    short* qkb   = (short*)ws;                                 // 2 MB  bf16 [N][128]
    short* vtb   = (short*)(ws + (2u << 20));                  // 2 MB  bf16 [128][N]
    short* wqb   = (short*)(ws + (4u << 20));                  // 256 KB
    short* wvb   = (short*)(ws + (4u << 20) + (256u << 10));   // 256 KB
    float* lpart = (float*)(ws + (4u << 20) + (512u << 10));   // 256 KB fp32 [KS][N]
    float* opart = (float*)(ws + (5u << 20));                  // 32 MB fp32 [KS][N][128]

    wconv_kernel<<<dim3(128), 256, 0, stream>>>(Wqk, Wv, wqb, wvb);
    proj_kernel<<<dim3(NROWS / 32), 512, 0, stream>>>(x, wqb, bqk, wvb, bv, qkb, vtb);
    flash_kernel<<<dim3(NROWS / 128, KSPLIT), 256, 0, stream>>>(qkb, vtb, opart, lpart);
    combine_kernel<<<dim3(NROWS * DKV / 256), 256, 0, stream>>>(opart, lpart, out);
}